// Round 9
// baseline (211.192 us; speedup 1.0000x reference)
//
#include <hip/hip_runtime.h>

// KAN layer fused as one augmented GEMM:
//   out[n][o] = sum_i silu(x[n][i])*scale_base[o][i]
//            + sum_{i,m} basis_m(x[n][i])*scale_sp[o][i]*coef[o][i][m] + bias[o]
//
// R9: K-PERMUTED augmented layout k' = i*7 + j (j=0: silu, j=1..6: basis).
// The GEMM is invariant to K-order (A and W share the permutation) -> kan_gemm
// is byte-identical to R5/R8 (proven 93-97 us). The permutation makes BOTH
// build writes fully contiguous (56 consecutive f16 per thread, 7 KB per wave)
// instead of 7 streams strided by 1536 B -- the hypothesized cause of the
// invariant ~95 us non-GEMM residual across 3 build rewrites.

typedef _Float16 f16;
typedef __attribute__((ext_vector_type(8))) _Float16 f16x8;
typedef __attribute__((ext_vector_type(4))) float f32x4;

#define NTOK 8192
#define DIN 768
#define DOUT 768
#define KAUG 5376        // 7*768
#define BM 128
#define BN 192
#define BK 64
#define NKT (KAUG / BK)  // 84 K-tiles
#define ASZ (BM * BK)    // 8192 f16 = 16 KB
#define BSZ (BN * BK)    // 12288 f16 = 24 KB
#define NBLK ((NTOK / BM) * (DOUT / BN))  // 64*4 = 256 blocks

typedef __attribute__((address_space(1))) void gvoid;
typedef __attribute__((address_space(3))) void lvoid;

// ---------------- silu + 6 basis values for one x ----------------
__device__ __forceinline__ void spline6(float xv, float* __restrict__ B, float& s) {
  s = xv / (1.0f + __expf(-xv));  // silu
  const float h = 2.0f / 3.0f;
  float Bb[9];
#pragma unroll
  for (int g = 0; g < 9; ++g) {
    float t0 = (float)(g - 3) * h - 1.0f;
    float t1 = (float)(g - 2) * h - 1.0f;
    Bb[g] = (xv >= t0 && xv < t1) ? 1.0f : 0.0f;
  }
#pragma unroll
  for (int p = 1; p <= 3; ++p) {
    float inv = 1.0f / ((float)p * h);
#pragma unroll
    for (int j = 0; j < 8; ++j) {
      if (j < 9 - p) {
        float tj = (float)(j - 3) * h - 1.0f;
        float tjp1 = (float)(j + p + 1 - 3) * h - 1.0f;
        Bb[j] = (xv - tj) * inv * Bb[j] + (tjp1 - xv) * inv * Bb[j + 1];
      }
    }
  }
#pragma unroll
  for (int m = 0; m < 6; ++m) B[m] = Bb[m];
}

#define NBLK_A ((NTOK * DIN) / 2048)  // 3072 blocks (8 i's per thread)
#define NBLK_W ((DOUT * DIN) / 2048)  // 288 blocks  (8 i's per thread)

// ---------------- Kernel 1: build A_aug and W_aug, CONTIGUOUS writes ----------------
// A[n][i*7+j], W[o][i*7+j]. Per thread: 8 consecutive i -> 56 consecutive f16
// = 7 aligned f16x8 stores (base byte = n*10752 + i0*14; i0%8==0 -> 16B-aligned).
__global__ __launch_bounds__(256) void build_AW(const float* __restrict__ x,
                                                const float* __restrict__ sb,
                                                const float* __restrict__ ssp,
                                                const float* __restrict__ coef,
                                                f16* __restrict__ Aa,
                                                f16* __restrict__ Wa) {
  const int b = blockIdx.x;
  if (b < NBLK_A) {
    int idx = (b * 256 + threadIdx.x) * 8;  // 8 consecutive i, same n (768%8==0)
    float4 x0 = *(const float4*)(x + idx);
    float4 x1 = *(const float4*)(x + idx + 4);
    float xs[8] = {x0.x, x0.y, x0.z, x0.w, x1.x, x1.y, x1.z, x1.w};
    int n = idx / DIN;
    int i0 = idx - n * DIN;

    float Bv[8][6], sv[8];
#pragma unroll
    for (int t = 0; t < 8; ++t) spline6(xs[t], Bv[t], sv[t]);

    f16* dst = Aa + (size_t)n * KAUG + (size_t)i0 * 7;  // 56 consecutive f16
#pragma unroll
    for (int s = 0; s < 7; ++s) {
      f16x8 v;
#pragma unroll
      for (int u = 0; u < 8; ++u) {
        const int e = s * 8 + u;     // 0..55
        const int t = e / 7;         // i within group
        const int j = e % 7;         // 0: silu, 1..6: basis
        v[u] = (f16)(j == 0 ? sv[t] : Bv[t][j - 1]);
      }
      *(f16x8*)(dst + s * 8) = v;
    }
  } else {
    int idx = ((b - NBLK_A) * 256 + threadIdx.x) * 8;  // 8 consecutive i, same o
    float4 b0 = *(const float4*)(sb + idx);
    float4 b1 = *(const float4*)(sb + idx + 4);
    float4 p0 = *(const float4*)(ssp + idx);
    float4 p1 = *(const float4*)(ssp + idx + 4);
    float bs[8] = {b0.x, b0.y, b0.z, b0.w, b1.x, b1.y, b1.z, b1.w};
    float ps[8] = {p0.x, p0.y, p0.z, p0.w, p1.x, p1.y, p1.z, p1.w};
    int o = idx / DIN;
    int i0 = idx - o * DIN;
    // coef[o][i0..i0+8][0..6): 48 consecutive f32, 16B-aligned (idx*6 % 4 == 0)
    float c[48];
#pragma unroll
    for (int j = 0; j < 12; ++j) {
      float4 cv = *(const float4*)(coef + (size_t)idx * 6 + j * 4);
      c[j * 4 + 0] = cv.x; c[j * 4 + 1] = cv.y; c[j * 4 + 2] = cv.z; c[j * 4 + 3] = cv.w;
    }

    f16* dst = Wa + (size_t)o * KAUG + (size_t)i0 * 7;  // 56 consecutive f16
#pragma unroll
    for (int s = 0; s < 7; ++s) {
      f16x8 v;
#pragma unroll
      for (int u = 0; u < 8; ++u) {
        const int e = s * 8 + u;
        const int t = e / 7;
        const int j = e % 7;
        v[u] = (f16)(j == 0 ? bs[t] : ps[t] * c[t * 6 + (j - 1)]);
      }
      *(f16x8*)(dst + s * 8) = v;
    }
  }
}

// ---------------- Kernel 2: GEMM C = A_aug * W_aug^T + bias (exact R5/R8) ----------------
// LDS content: buf[row][slot] = G[row][slot ^ (row&7)] (slot = 8-f16 group of K).
// global_load_lds dest linear (chunk c -> 16B at c*16); per-lane GLOBAL src is
// pre-swizzled. Reads apply the same XOR -> conflict-free.
// Schedule per K-tile t (3-buf: prefetch target never concurrently read):
//   ph0: ds_read af/bf[kh=0] | stage B(t+2) | 12 MFMA | lgkmcnt(0) barrier
//   ph1: ds_read af/bf[kh=1] | stage A(t+2) | 12 MFMA | lgkmcnt(0) vmcnt(5) barrier
__global__ __launch_bounds__(512, 2) void kan_gemm(const f16* __restrict__ A,
                                                   const f16* __restrict__ W,
                                                   const float* __restrict__ bias,
                                                   float* __restrict__ out) {
  __shared__ alignas(16) f16 As[3 * ASZ];  // 48 KB
  __shared__ alignas(16) f16 Bs[3 * BSZ];  // 72 KB  (120 KB total, 1 block/CU)

  const int tid = threadIdx.x;
  const int wave = tid >> 6;
  const int lane = tid & 63;

  // XCD-chunked swizzle: 256 % 8 == 0 -> bijective. Each XCD: 8 M-panels x 4 cols.
  const int bid = blockIdx.x;
  const int wg = (bid & 7) * (NBLK / 8) + (bid >> 3);
  const int m0 = (wg >> 2) * BM;
  const int n0 = (wg & 3) * BN;

  const int wm = (wave >> 2) * 64;  // 2 M-waves
  const int wn = (wave & 3) * 48;   // 4 N-waves
  const int r = lane & 15;
  const int q = lane >> 4;
  const int r7 = r & 7;

  f32x4 acc[4][3] = {};

  // ---- staging source pointers (chunk c: row = c>>3, lds slot = c&7,
  //      global slot = (c&7) ^ (row&7)) ----
  const int cA0 = tid, cA1 = tid + 512;
  const int cB0 = tid, cB1 = tid + 512, cB2 = tid + 1024;
  const f16* gA0 = A + (size_t)(m0 + (cA0 >> 3)) * KAUG + ((cA0 & 7) ^ ((cA0 >> 3) & 7)) * 8;
  const f16* gA1 = A + (size_t)(m0 + (cA1 >> 3)) * KAUG + ((cA1 & 7) ^ ((cA1 >> 3) & 7)) * 8;
  const f16* gB0 = W + (size_t)(n0 + (cB0 >> 3)) * KAUG + ((cB0 & 7) ^ ((cB0 >> 3) & 7)) * 8;
  const f16* gB1 = W + (size_t)(n0 + (cB1 >> 3)) * KAUG + ((cB1 & 7) ^ ((cB1 >> 3) & 7)) * 8;
  const f16* gB2 = W + (size_t)(n0 + (cB2 >> 3)) * KAUG + ((cB2 & 7) ^ ((cB2 >> 3) & 7)) * 8;
  // wave-uniform LDS dests (f16 units); HW adds lane*16B
  const int dA0 = wave * 512, dA1 = 4096 + wave * 512;
  const int dB0 = wave * 512, dB1 = 4096 + wave * 512, dB2 = 8192 + wave * 512;

#define STAGE_B(bufi, kt)                                                                  \
  do {                                                                                     \
    const int ko = (kt)*BK;                                                                \
    f16* bb_ = Bs + (bufi)*BSZ;                                                            \
    __builtin_amdgcn_global_load_lds((gvoid*)(gB0 + ko), (lvoid*)(bb_ + dB0), 16, 0, 0);   \
    __builtin_amdgcn_global_load_lds((gvoid*)(gB1 + ko), (lvoid*)(bb_ + dB1), 16, 0, 0);   \
    __builtin_amdgcn_global_load_lds((gvoid*)(gB2 + ko), (lvoid*)(bb_ + dB2), 16, 0, 0);   \
  } while (0)

#define STAGE_A(bufi, kt)                                                                  \
  do {                                                                                     \
    const int ko = (kt)*BK;                                                                \
    f16* ab_ = As + (bufi)*ASZ;                                                            \
    __builtin_amdgcn_global_load_lds((gvoid*)(gA0 + ko), (lvoid*)(ab_ + dA0), 16, 0, 0);   \
    __builtin_amdgcn_global_load_lds((gvoid*)(gA1 + ko), (lvoid*)(ab_ + dA1), 16, 0, 0);   \
  } while (0)

  // one phase: ds_read the kh-half subtile, issue stage, MFMA cluster
#define PH(bufi, kh, STAGE_STMT)                                                           \
  do {                                                                                     \
    const f16* Ab = As + (bufi)*ASZ;                                                       \
    const f16* Bb = Bs + (bufi)*BSZ;                                                       \
    const int sl = (((kh)*4 + q) ^ r7) * 8;                                                \
    f16x8 af[4], bf[3];                                                                    \
    _Pragma("unroll") for (int mi = 0; mi < 4; ++mi) af[mi] =                              \
        *(const f16x8*)&Ab[(wm + mi * 16 + r) * BK + sl];                                  \
    _Pragma("unroll") for (int ni = 0; ni < 3; ++ni) bf[ni] =                              \
        *(const f16x8*)&Bb[(wn + ni * 16 + r) * BK + sl];                                  \
    STAGE_STMT;                                                                            \
    __builtin_amdgcn_s_setprio(1);                                                         \
    _Pragma("unroll") for (int mi = 0; mi < 4; ++mi)                                       \
        _Pragma("unroll") for (int ni = 0; ni < 3; ++ni) acc[mi][ni] =                     \
        __builtin_amdgcn_mfma_f32_16x16x32_f16(af[mi], bf[ni], acc[mi][ni], 0, 0, 0);      \
    __builtin_amdgcn_s_setprio(0);                                                         \
  } while (0)

  // end-of-iteration fence: ds_reads of this iter complete + staged tile t+1
  // landed (counted vmcnt, never 0 in loop), then barrier.
#define FENCE_BAR(VMC)                                            \
  do {                                                            \
    asm volatile("s_waitcnt lgkmcnt(0) vmcnt(" #VMC ")" ::: "memory"); \
    __builtin_amdgcn_sched_barrier(0);                            \
    __builtin_amdgcn_s_barrier();                                 \
  } while (0)

#define MID_BAR()                                                 \
  do {                                                            \
    asm volatile("s_waitcnt lgkmcnt(0)" ::: "memory");            \
    __builtin_amdgcn_sched_barrier(0);                            \
    __builtin_amdgcn_s_barrier();                                 \
  } while (0)

  // prologue: stage tiles 0 and 1 (issue order matters for vmcnt accounting)
  STAGE_B(0, 0);
  STAGE_A(0, 0);
  STAGE_B(1, 1);
  STAGE_A(1, 1);
  FENCE_BAR(5);  // tile 0 fully landed (5 newest = tile 1's loads)

  for (int t = 0; t < NKT - 2; ++t) {  // t = 0..81, stages t+2 in [2,83]
    const int rb = t % 3;
    const int pb = (t + 2) % 3;
    PH(rb, 0, STAGE_B(pb, t + 2));
    MID_BAR();
    PH(rb, 1, STAGE_A(pb, t + 2));
    FENCE_BAR(5);  // tile t+1 fully landed
  }
  {  // t = 82: no staging; drain for final tile
    const int rb = (NKT - 2) % 3;
    PH(rb, 0, (void)0);
    MID_BAR();
    PH(rb, 1, (void)0);
    FENCE_BAR(0);
  }
  {  // t = 83
    const int rb = (NKT - 1) % 3;
    PH(rb, 0, (void)0);
    PH(rb, 1, (void)0);
  }

#undef STAGE_A
#undef STAGE_B
#undef PH
#undef FENCE_BAR
#undef MID_BAR

  // epilogue: D mapping col = lane&15, row = q*4 + reg; bias fused
#pragma unroll
  for (int mi = 0; mi < 4; ++mi) {
#pragma unroll
    for (int ni = 0; ni < 3; ++ni) {
      const int gcol = n0 + wn + ni * 16 + r;
      const float bv = bias[gcol];
#pragma unroll
      for (int rg = 0; rg < 4; ++rg) {
        const int grow = m0 + wm + mi * 16 + q * 4 + rg;
        out[(size_t)grow * DOUT + gcol] = acc[mi][ni][rg] + bv;
      }
    }
  }
}

extern "C" void kernel_launch(void* const* d_in, const int* in_sizes, int n_in,
                              void* d_out, int out_size, void* d_ws, size_t ws_size,
                              hipStream_t stream) {
  const float* x = (const float*)d_in[0];           // (4,2048,768)
  const float* coef = (const float*)d_in[1];        // (768,768,6)
  const float* scale_base = (const float*)d_in[2];  // (768,768)
  const float* scale_sp = (const float*)d_in[3];    // (768,768)
  const float* bias = (const float*)d_in[4];        // (768,)
  float* out = (float*)d_out;                       // (8192,768)

  f16* Aa = (f16*)d_ws;                                     // 8192*5376*2 = 88.1 MB
  f16* Wa = (f16*)((char*)d_ws + (size_t)NTOK * KAUG * 2);  // 768*5376*2  = 8.3 MB

  build_AW<<<NBLK_A + NBLK_W, 256, 0, stream>>>(x, scale_base, scale_sp, coef, Aa, Wa);
  kan_gemm<<<NBLK, 512, 0, stream>>>(Aa, Wa, bias, out);
}